// Round 7
// baseline (98.831 us; speedup 1.0000x reference)
//
#include <hip/hip_runtime.h>

// RelativePositionalEncoding:
//   out[b,i,j,k] = W[k][clip(index[b,i]-index[b,j]+32, 0, 64)] + bias[k]
//   B=4, N=2048, ATTN_DIM=8, N_REL_POS=65
//
// 512 MiB fp32 output, ~40 KB inputs -> pure HBM-write-bound.
// Round 7: saturated-region fast path. c = idx_i - idx_j + 32 saturates to
// 0 or 64 everywhere except a 65-wide diagonal band, and saturation is
// wave-uniform per 32-j chunk for monotone index data (~97% of chunks here).
// Wave-uniform __all() branch stores a register constant (vhi/vlo) with NO
// LDS read -> hot loop is instruction-equivalent to fillBuffer (85% peak).
// Mixed chunks still take the exact LDS gather, so the kernel is correct
// for arbitrary index inputs.

#define MAX_REL 32
#define NRP 65          // 2*MAX_REL + 1
#define AD 8            // ATTN_DIM
#define ROWS 4
#define BLK 256
#define SLOTS 16        // fast path: N*2/BLK == 16  (N == 2048)

typedef float f4 __attribute__((ext_vector_type(4)));

__global__ __launch_bounds__(BLK, 8) void relpos_kernel(
    const int* __restrict__ index,
    const float* __restrict__ W,      // [AD][NRP]
    const float* __restrict__ bias,   // [AD]
    float* __restrict__ out,          // [B][N][N][AD]
    int N)
{
    extern __shared__ char smem[];
    float* s_tabf = (float*)smem;                            // [NRP][AD] fused W.T + b
    f4*    s_tab4 = (f4*)smem;
    int*   s_idx  = (int*)(smem + NRP * AD * sizeof(float)); // [N] (generic path only)

    const int tid = threadIdx.x;
    const int i0  = blockIdx.x * ROWS;
    const int bb  = blockIdx.y;
    const int* irow = index + (size_t)bb * (size_t)N;

    for (int t = tid; t < NRP * AD; t += BLK) {
        int p = t >> 3;
        int k = t & 7;
        s_tabf[t] = W[k * NRP + p] + bias[k];
    }

    const int vecs = N * 2;  // float4 chunks per output row
    f4* obase = (f4*)out + ((size_t)bb * (size_t)N + (size_t)i0) * (size_t)(N * 2);

    if (vecs == SLOTS * BLK && (N % ROWS) == 0) {
        // ---- fast path (N == 2048) ----
        const int wave = tid >> 6;
        const int lane = tid & 63;
        const int par  = lane & 1;       // which half of the f4-pair
        const int jrow = (lane >> 1);    // 0..31

        // This thread's SLOTS index values, direct from global (coalesced).
        int sj[SLOTS];
        #pragma unroll
        for (int k = 0; k < SLOTS; ++k)
            sj[k] = irow[wave * 512 + k * 32 + jrow];

        int idx_i[ROWS];
        #pragma unroll
        for (int r = 0; r < ROWS; ++r)
            idx_i[r] = irow[i0 + r] + MAX_REL;

        __syncthreads();   // table ready

        // Register-held saturated values.
        const f4 vlo = s_tab4[par];                  // c == 0
        const f4 vhi = s_tab4[(NRP - 1) * 2 + par];  // c == 64

        #pragma unroll
        for (int r = 0; r < ROWS; ++r) {
            f4* wbase = obase + (size_t)r * (size_t)vecs + wave * 1024 + lane;
            #pragma unroll
            for (int k = 0; k < SLOTS; ++k) {
                int c = idx_i[r] - sj[k];
                f4 v;
                if (__all(c >= NRP - 1)) {
                    v = vhi;                          // no LDS dependency
                } else if (__all(c <= 0)) {
                    v = vlo;                          // no LDS dependency
                } else {
                    c = c < 0 ? 0 : (c > NRP - 1 ? NRP - 1 : c);
                    v = s_tab4[c * 2 + par];          // exact gather (band)
                }
                wbase[k * 64] = v;                    // +1 KB per k
            }
        }
    } else {
        // ---- generic path: LDS-staged index row ----
        for (int t = tid; t < N; t += BLK)
            s_idx[t] = irow[t];
        __syncthreads();

        for (int r = 0; r < ROWS; ++r) {
            const int i = i0 + r;
            if (i >= N) break;
            const int ii = s_idx[i] + MAX_REL;
            f4* orow = obase + (size_t)r * (size_t)vecs;
            for (int f = tid; f < vecs; f += BLK) {
                int c = ii - s_idx[f >> 1];
                c = c < 0 ? 0 : (c > NRP - 1 ? NRP - 1 : c);
                f4 v = s_tab4[c * 2 + (f & 1)];
                orow[f] = v;
            }
        }
    }
}

extern "C" void kernel_launch(void* const* d_in, const int* in_sizes, int n_in,
                              void* d_out, int out_size, void* d_ws, size_t ws_size,
                              hipStream_t stream) {
    const int*   index = (const int*)d_in[0];
    const float* W     = (const float*)d_in[1];
    const float* bias  = (const float*)d_in[2];
    float*       out   = (float*)d_out;

    const long long BN = in_sizes[0];                       // B * N
    const long long N  = (long long)out_size / (BN * AD);   // out = B*N*N*AD
    const long long B  = BN / N;

    const size_t smem = NRP * AD * sizeof(float) + (size_t)N * sizeof(int);
    dim3 grid((unsigned)((N + ROWS - 1) / ROWS), (unsigned)B, 1);
    relpos_kernel<<<grid, BLK, smem, stream>>>(index, W, bias, out, (int)N);
}

// Round 8
// 96.141 us; speedup vs baseline: 1.0280x; 1.0280x over previous
//
#include <hip/hip_runtime.h>

// RelativePositionalEncoding:
//   out[b,i,j,k] = W[k][clip(index[b,i]-index[b,j]+32, 0, 64)] + bias[k]
//   B=4, N=2048, ATTN_DIM=8, N_REL_POS=65
//
// 512 MiB fp32 output, ~40 KB inputs -> pure HBM-write-bound.
// FINAL (= round 6, best measured: 96.4 us, ~5.6 TB/s gross, ~6.2 TB/s net
// of launch/prologue overhead -> at the ~6.3 TB/s achievable write ceiling).
//   - fused table (W.T + b) staged once per block in LDS
//   - index values register-cached via direct coalesced global loads
//   - per-wave contiguous 16 KB store runs, plain cached dwordx4 stores
//   - ROWS=4 -> 2048 blocks = 8 blocks/CU = full 32-wave occupancy
//   - fully unrolled 4x16 store burst, no row-loop break
// Tested and rejected: nontemporal stores (-3%), saturated-region uniform
// branch (-2.5%), LDS index staging (neutral), strided store partition (-2%).

#define MAX_REL 32
#define NRP 65          // 2*MAX_REL + 1
#define AD 8            // ATTN_DIM
#define ROWS 4
#define BLK 256
#define SLOTS 16        // fast path: N*2/BLK == 16  (N == 2048)

typedef float f4 __attribute__((ext_vector_type(4)));

__global__ __launch_bounds__(BLK, 8) void relpos_kernel(
    const int* __restrict__ index,
    const float* __restrict__ W,      // [AD][NRP]
    const float* __restrict__ bias,   // [AD]
    float* __restrict__ out,          // [B][N][N][AD]
    int N)
{
    extern __shared__ char smem[];
    float* s_tabf = (float*)smem;                            // [NRP][AD] fused W.T + b
    f4*    s_tab4 = (f4*)smem;
    int*   s_idx  = (int*)(smem + NRP * AD * sizeof(float)); // [N] (generic path only)

    const int tid = threadIdx.x;
    const int i0  = blockIdx.x * ROWS;
    const int bb  = blockIdx.y;
    const int* irow = index + (size_t)bb * (size_t)N;

    for (int t = tid; t < NRP * AD; t += BLK) {
        int p = t >> 3;
        int k = t & 7;
        s_tabf[t] = W[k * NRP + p] + bias[k];
    }

    const int vecs = N * 2;  // float4 chunks per output row
    f4* obase = (f4*)out + ((size_t)bb * (size_t)N + (size_t)i0) * (size_t)(N * 2);

    if (vecs == SLOTS * BLK && (N % ROWS) == 0) {
        // ---- fast path (N == 2048): no index staging, no row-loop break ----
        const int wave = tid >> 6;
        const int lane = tid & 63;
        const int par  = lane & 1;       // which half of the f4-pair
        const int jrow = (lane >> 1);    // 0..31

        // Direct global loads of this thread's SLOTS index values.
        // Per instruction: 64 lanes read 32 consecutive ints (2-way dup) = 128B.
        int sj[SLOTS];
        #pragma unroll
        for (int k = 0; k < SLOTS; ++k)
            sj[k] = irow[wave * 512 + k * 32 + jrow];

        // Uniform scalar loads of the row indices.
        int idx_i[ROWS];
        #pragma unroll
        for (int r = 0; r < ROWS; ++r)
            idx_i[r] = irow[i0 + r] + MAX_REL;

        __syncthreads();   // table ready

        #pragma unroll
        for (int r = 0; r < ROWS; ++r) {
            // wave's contiguous 16 KB run within this 64 KB row
            f4* wbase = obase + (size_t)r * (size_t)vecs + wave * 1024 + lane;
            #pragma unroll
            for (int k = 0; k < SLOTS; ++k) {
                int c = idx_i[r] - sj[k];
                c = c < 0 ? 0 : (c > NRP - 1 ? NRP - 1 : c);
                f4 v = s_tab4[c * 2 + par];
                wbase[k * 64] = v;       // +1 KB per k -> offset immediates
            }
        }
    } else {
        // ---- generic path: LDS-staged index row ----
        for (int t = tid; t < N; t += BLK)
            s_idx[t] = irow[t];
        __syncthreads();

        for (int r = 0; r < ROWS; ++r) {
            const int i = i0 + r;
            if (i >= N) break;
            const int ii = s_idx[i] + MAX_REL;
            f4* orow = obase + (size_t)r * (size_t)vecs;
            for (int f = tid; f < vecs; f += BLK) {
                int c = ii - s_idx[f >> 1];
                c = c < 0 ? 0 : (c > NRP - 1 ? NRP - 1 : c);
                f4 v = s_tab4[c * 2 + (f & 1)];
                orow[f] = v;
            }
        }
    }
}

extern "C" void kernel_launch(void* const* d_in, const int* in_sizes, int n_in,
                              void* d_out, int out_size, void* d_ws, size_t ws_size,
                              hipStream_t stream) {
    const int*   index = (const int*)d_in[0];
    const float* W     = (const float*)d_in[1];
    const float* bias  = (const float*)d_in[2];
    float*       out   = (float*)d_out;

    const long long BN = in_sizes[0];                       // B * N
    const long long N  = (long long)out_size / (BN * AD);   // out = B*N*N*AD
    const long long B  = BN / N;

    const size_t smem = NRP * AD * sizeof(float) + (size_t)N * sizeof(int);
    dim3 grid((unsigned)((N + ROWS - 1) / ROWS), (unsigned)B, 1);
    relpos_kernel<<<grid, BLK, smem, stream>>>(index, W, bias, out, (int)N);
}